// Round 8
// baseline (122.242 us; speedup 1.0000x reference)
//
#include <hip/hip_runtime.h>
#include <hip/hip_bf16.h>

// GraphConvPooling: y = (A @ x) @ W + b ; pooled = max_rows(y) ; MLP(tanh,tanh,lin)
// A is DEDUPLICATED 0/1 adjacency (.set semantics). Reassociated: y = A@(x@W)+b.
//
// Tier A (ws >= ~33MB), no global atomics in build, LDS-tiled gather:
//   bin(+pooled/done clear) -> xw GEMM (XCD-swizzled writes)
//   -> agg_tiled(drain->LDS mask->lists, 8x32KB xw source tiles in LDS,
//      register accumulators, last-block-fused MLP) ; 2 dispatches + bin.
// Tier B (ws >= ~8.4MB): round-3 proven bitmask path. Tier C: zero-ws fused.
//
// B=64 graphs, N=1024 nodes/graph, D=64. edge_index arrives as INT32.

#define NNODES 65536
#define NGRAPH 64
#define NLOCAL 1024
#define DIM 64
#define MASK_WORDS 32   // 1024 bits / 32
#define KMAX 64         // max deduped out-degree kept (P(deg>64) ~ e^-16)
#define CHUNK_ROWS 128  // dest rows per agg block / bucket
#define TILE_ROWS 128   // src rows per LDS tile
#define NTILE 8         // 1024 / TILE_ROWS
#define NBIN 256        // bin blocks
#define NBUCKET 512     // 64 graphs x 8 chunks of 128 rows
#define SEGCAP 32       // slots per (bin,bucket) segment: mean 8, P(>32)~1e-11

__device__ __forceinline__ unsigned f2ord(float f) {
    unsigned u = __float_as_uint(f);
    return (u & 0x80000000u) ? ~u : (u | 0x80000000u);
}
__device__ __forceinline__ float ord2f(unsigned u) {
    return (u & 0x80000000u) ? __uint_as_float(u & 0x7FFFFFFFu)
                             : __uint_as_float(~u);
}

__global__ __launch_bounds__(256) void clear_kernel(uint4* __restrict__ p, int n4)
{
    int i = blockIdx.x * 256 + threadIdx.x;
    int stride = gridDim.x * 256;
    uint4 z = {0u, 0u, 0u, 0u};
    for (; i < n4; i += stride) p[i] = z;
}

// Privatized binning: block b owns seg[b][bucket][SEGCAP] (128B, line-aligned,
// written ONLY by b -> plain stores, no global atomics). Also zeroes pooled+done.
// bucket = g*8 + (s_loc>>7). Payload = (s_loc<<10)|t_loc.
__global__ __launch_bounds__(256) void bin_kernel(
    const int* __restrict__ ei, int E,
    unsigned* __restrict__ seg, unsigned short* __restrict__ segcnt,
    unsigned* __restrict__ pooled_u, unsigned* __restrict__ done)
{
    __shared__ unsigned off[NBUCKET];
    int tid = threadIdx.x;
    off[tid] = 0u;
    off[tid + 256] = 0u;
    if (blockIdx.x < 16) pooled_u[blockIdx.x * 256 + tid] = 0u;  // folded clear
    if (blockIdx.x == 16 && tid == 0) *done = 0u;
    __syncthreads();
    int perblk = (E + NBIN - 1) / NBIN;
    int e0 = blockIdx.x * perblk;
    int e1 = min(e0 + perblk, E);
    unsigned* myseg = seg + (size_t)blockIdx.x * NBUCKET * SEGCAP;
    for (int e = e0 + tid; e < e1; e += 256) {
        int s = ei[e];
        int t = ei[E + e] & (NLOCAL - 1);
        int sl = s & (NLOCAL - 1);
        int bk = ((s >> 10) << 3) | (sl >> 7);
        unsigned slot = atomicAdd(&off[bk], 1u);       // LDS atomic
        if (slot < SEGCAP) myseg[bk * SEGCAP + slot] = (unsigned)((sl << 10) | t);
    }
    __syncthreads();
    unsigned c0 = off[tid], c1 = off[tid + 256];
    segcnt[blockIdx.x * NBUCKET + tid]       = (unsigned short)(c0 < SEGCAP ? c0 : SEGCAP);
    segcnt[blockIdx.x * NBUCKET + tid + 256] = (unsigned short)(c1 < SEGCAP ? c1 : SEGCAP);
}

// xw = x @ W, XCD-swizzled so graph g's rows are written by blocks with
// blockIdx%8 == g%8 (same XCD that agg's blocks for g will run on).
__global__ __launch_bounds__(256) void xw_kernel(
    const float* __restrict__ x, const float* __restrict__ W,
    float* __restrict__ xw)
{
    __shared__ float4 xlds[64 * 16];
    int tid = threadIdx.x;
    int b = blockIdx.x;                  // 1024 blocks
    int xcd = b & 7, idx = b >> 3;       // idx 0..127
    int g = ((idx >> 4) << 3) | xcd;     // g%8 == xcd
    int sub = idx & 15;                  // 16 x 64-row sub-blocks per graph
    int row0 = (g << 10) + (sub << 6);

    const float4* xg4 = (const float4*)(x + (size_t)row0 * DIM);
    for (int i = tid; i < 64 * 16; i += 256) xlds[i] = xg4[i];
    int col = tid & 63;
    int rg  = tid >> 6;
    float w[64];
    #pragma unroll
    for (int k = 0; k < 64; ++k) w[k] = W[k * DIM + col];
    __syncthreads();
    #pragma unroll
    for (int rr = 0; rr < 16; ++rr) {
        int row = rg * 16 + rr;
        float acc = 0.f;
        #pragma unroll
        for (int k4 = 0; k4 < 16; ++k4) {
            float4 xv = xlds[row * 16 + k4];
            acc = fmaf(xv.x, w[4 * k4 + 0], acc);
            acc = fmaf(xv.y, w[4 * k4 + 1], acc);
            acc = fmaf(xv.z, w[4 * k4 + 2], acc);
            acc = fmaf(xv.w, w[4 * k4 + 3], acc);
        }
        xw[(size_t)(row0 + row) * DIM + col] = acc;
    }
}

// One block per (graph, 128-row dest chunk), 1024 thr (16 waves x 8 rows).
// Gathers come from LDS source tiles (8 x 32KB), not L2 -> ~70cy latency.
// Last block (device atomic counter) runs the MLP across its 16 waves.
__global__ __launch_bounds__(1024) void agg_tiled_kernel(
    const float* __restrict__ xw, const float* __restrict__ bias,
    const unsigned* __restrict__ seg, const unsigned short* __restrict__ segcnt,
    unsigned* __restrict__ pooled_u, unsigned* __restrict__ done,
    const float* __restrict__ w1, const float* __restrict__ b1,
    const float* __restrict__ w2, const float* __restrict__ b2,
    const float* __restrict__ w3, const float* __restrict__ b3,
    float* __restrict__ out)
{
    __shared__ unsigned mask[CHUNK_ROWS * MASK_WORDS];   // 16KB; becomes lists
    __shared__ float tile[TILE_ROWS * DIM];              // 32KB
    __shared__ float red[16 * DIM];                      // 4KB
    __shared__ unsigned lastflag;

    int tid = threadIdx.x;
    int lane = tid & 63, wave = tid >> 6;
    int b = blockIdx.x;
    int g = ((b >> 6) << 3) | (b & 7);   // g%8 == blockIdx%8 -> XCD locality
    int chunk = (b >> 3) & 7;
    int bk = (g << 3) | chunk;

    for (int i = tid; i < CHUNK_ROWS * MASK_WORDS; i += 1024) mask[i] = 0u;
    __syncthreads();

    // drain all bins' segments for this bucket into the LDS dedup mask
    for (int idx0 = tid; idx0 < NBIN * SEGCAP; idx0 += 1024) {
        int sb = idx0 >> 5;
        int sl = idx0 & 31;
        int n = segcnt[sb * NBUCKET + bk];
        if (sl < n) {
            unsigned pk = seg[((size_t)sb * NBUCKET + bk) * SEGCAP + sl];
            int r = (pk >> 10) & (CHUNK_ROWS - 1);
            int t = pk & (NLOCAL - 1);
            atomicOr(&mask[r * MASK_WORDS + (t >> 5)], 1u << (t & 31));
        }
    }
    __syncthreads();

    // extract sorted u16 lists in place (pairs, half-wave per row; wave-local)
    unsigned short* lists = (unsigned short*)mask;
    int cc[8];
    #pragma unroll
    for (int i = 0; i < 8; i += 2) {
        int rowa = wave * 8 + i;
        int myrow = rowa + ((lane >> 5) & 1);
        unsigned bits = mask[myrow * MASK_WORDS + (lane & 31)];
        int c = __popc(bits);
        int inc = c;
        #pragma unroll
        for (int d = 1; d < 32; d <<= 1) {
            int v = __shfl_up(inc, d, 32);
            if ((lane & 31) >= d) inc += v;
        }
        int off = inc - c;
        unsigned short* lr = lists + myrow * KMAX;
        while (bits) {
            int bb = __ffs(bits) - 1;
            bits &= bits - 1;
            if (off < KMAX) lr[off] = (unsigned short)((lane & 31) * 32 + bb);
            ++off;
        }
        int cca = __shfl(inc, 31, 64);
        int ccb = __shfl(inc, 63, 64);
        cc[i]     = cca < KMAX ? cca : KMAX;
        cc[i + 1] = ccb < KMAX ? ccb : KMAX;
    }

    const float* xwg = xw + ((size_t)g << 10) * DIM;
    float acc[8];
    int idx[8];
    #pragma unroll
    for (int i = 0; i < 8; ++i) { acc[i] = 0.f; idx[i] = 0; }

    for (int k = 0; k < NTILE; ++k) {
        __syncthreads();                 // prior walk done before overwrite
        const float4* src = (const float4*)(xwg + (size_t)k * TILE_ROWS * DIM);
        float4* dst = (float4*)tile;
        dst[tid] = src[tid];             // 2048 float4 = 32KB, coalesced
        dst[tid + 1024] = src[tid + 1024];
        __syncthreads();
        int hi = (k + 1) * TILE_ROWS;
        int base = k * TILE_ROWS;
        #pragma unroll
        for (int i = 0; i < 8; ++i) {
            int row = wave * 8 + i;
            const unsigned short* lr = lists + row * KMAX;
            int j = idx[i], c = cc[i];
            float a = acc[i];
            while (j < c) {
                int t = lr[j];           // wave-uniform broadcast
                if (t >= hi) break;
                a += tile[(t - base) * DIM + lane];  // 2-way bank = free
                ++j;
            }
            acc[i] = a;
            idx[i] = j;
        }
    }

    float bv = bias[lane];
    float vmax = -INFINITY;
    #pragma unroll
    for (int i = 0; i < 8; ++i) vmax = fmaxf(vmax, acc[i] + bv);

    red[wave * DIM + lane] = vmax;
    __syncthreads();
    if (wave == 0) {
        float m = red[lane];
        #pragma unroll
        for (int w = 1; w < 16; ++w) m = fmaxf(m, red[w * DIM + lane]);
        atomicMax(&pooled_u[g * DIM + lane], f2ord(m));
    }
    // ---- last block runs the MLP (deterministic: pooled is complete) ----
    if (tid == 0) {
        __threadfence();                 // waits wave0's atomicMax (wave vmcnt)
        unsigned v = atomicAdd(done, 1u);
        lastflag = (v == NBUCKET - 1) ? 1u : 0u;
    }
    __syncthreads();
    if (lastflag) {
        // 16 waves x 4 graphs each
        for (int gg = 0; gg < 4; ++gg) {
            int g2 = wave * 4 + gg;
            float pl = ord2f(atomicOr(&pooled_u[g2 * DIM + lane], 0u)); // coherent read
            float h = b1[lane];
            for (int k2 = 0; k2 < 64; ++k2) {
                float a = __shfl(pl, k2, 64);
                h = fmaf(a, w1[k2 * DIM + lane], h);
            }
            h = tanhf(h);
            float h2 = b2[lane];
            for (int k2 = 0; k2 < 64; ++k2) {
                float a = __shfl(h, k2, 64);
                h2 = fmaf(a, w2[k2 * DIM + lane], h2);
            }
            h2 = tanhf(h2);
            float v2 = h2 * w3[lane];
            #pragma unroll
            for (int o = 32; o; o >>= 1) v2 += __shfl_down(v2, o, 64);
            if (lane == 0) out[g2] = v2 + b3[0];
        }
    }
}

__global__ __launch_bounds__(64) void mlp_kernel(
    const unsigned* __restrict__ pooled_u,
    const float* __restrict__ w1, const float* __restrict__ b1,
    const float* __restrict__ w2, const float* __restrict__ b2,
    const float* __restrict__ w3, const float* __restrict__ b3,
    float* __restrict__ out)
{
    __shared__ float buf[DIM];
    __shared__ float buf2[DIM];
    int g = blockIdx.x, l = threadIdx.x;
    buf[l] = ord2f(pooled_u[g * DIM + l]);
    __syncthreads();
    float h = b1[l];
    for (int k = 0; k < DIM; ++k) h = fmaf(buf[k], w1[k * DIM + l], h);
    buf2[l] = tanhf(h);
    __syncthreads();
    float h2 = b2[l];
    for (int k = 0; k < DIM; ++k) h2 = fmaf(buf2[k], w2[k * DIM + l], h2);
    h2 = tanhf(h2);
    float v = h2 * w3[l];
    #pragma unroll
    for (int off = 32; off; off >>= 1) v += __shfl_down(v, off, 64);
    if (l == 0) out[g] = v + b3[0];
}

// ---- Tier B (round-3 proven): global bitmask + ffs + shfl matvec ----
__global__ __launch_bounds__(256) void scatter_kernel(
    const int* __restrict__ ei, unsigned* __restrict__ mask, int E)
{
    int e = blockIdx.x * 256 + threadIdx.x;
    if (e >= E) return;
    int start = ei[e];
    int col   = ei[E + e] & (NLOCAL - 1);
    atomicOr(&mask[(size_t)start * MASK_WORDS + (col >> 5)], 1u << (col & 31));
}

__global__ __launch_bounds__(256) void agg_kernel(
    const float* __restrict__ x, const float* __restrict__ weight,
    const float* __restrict__ bias, const unsigned* __restrict__ mask,
    unsigned* __restrict__ pooled_u)
{
    __shared__ float Wlds[DIM * DIM];
    __shared__ float blds[DIM];
    int tid = threadIdx.x;
    for (int i = tid; i < DIM * DIM; i += 256) Wlds[i] = weight[i];
    if (tid < DIM) blds[tid] = bias[tid];
    __syncthreads();
    int lane = tid & 63;
    int wave = tid >> 6;
    int rowbase = blockIdx.x * 64 + wave * 16;
    int g = rowbase >> 10;
    const float* xg = x + ((size_t)g << 10) * DIM;
    float vmax = -INFINITY;
    for (int rr = 0; rr < 16; ++rr) {
        int row = rowbase + rr;
        const unsigned* mrow = mask + (size_t)row * MASK_WORDS;
        float acc = 0.f;
        for (int w = 0; w < MASK_WORDS; ++w) {
            unsigned bits = mrow[w];
            while (bits) {
                int b = __ffs(bits) - 1;
                bits &= bits - 1;
                acc += xg[(size_t)(w * 32 + b) * DIM + lane];
            }
        }
        float y = blds[lane];
        for (int k = 0; k < DIM; ++k) {
            float a = __shfl(acc, k, 64);
            y = fmaf(a, Wlds[k * DIM + lane], y);
        }
        vmax = fmaxf(vmax, y);
    }
    atomicMax(&pooled_u[g * DIM + lane], f2ord(vmax));
}

// ---- Tier C: fused zero-workspace fallback ----
__global__ __launch_bounds__(1024) void fused_kernel(
    const float* __restrict__ x, const int* __restrict__ ei, int E,
    const float* __restrict__ weight, const float* __restrict__ bias,
    const float* __restrict__ w1, const float* __restrict__ b1,
    const float* __restrict__ w2, const float* __restrict__ b2,
    const float* __restrict__ w3, const float* __restrict__ b3,
    float* __restrict__ out)
{
    __shared__ unsigned mask[256 * MASK_WORDS];
    __shared__ float Wlds[DIM * DIM];
    __shared__ float blds[DIM];
    __shared__ float red[16 * DIM];
    __shared__ float pool[DIM];
    __shared__ float hbuf[DIM];
    int tid = threadIdx.x;
    int g = blockIdx.x;
    int lane = tid & 63;
    int wave = tid >> 6;
    const float* xg = x + ((size_t)g << 10) * DIM;
    for (int i = tid; i < DIM * DIM; i += 1024) Wlds[i] = weight[i];
    if (tid < DIM) blds[tid] = bias[tid];
    float vmax = -INFINITY;
    for (int chunk = 0; chunk < NLOCAL / 256; ++chunk) {
        int row0 = chunk * 256;
        __syncthreads();
        for (int i = tid; i < 256 * MASK_WORDS; i += 1024) mask[i] = 0u;
        __syncthreads();
        int lo = (g << 10) + row0, hi = lo + 256;
        for (int e = tid; e < E; e += 1024) {
            int s = ei[e];
            if (s >= lo && s < hi) {
                int t = ei[E + e] & (NLOCAL - 1);
                atomicOr(&mask[(s - lo) * MASK_WORDS + (t >> 5)], 1u << (t & 31));
            }
        }
        __syncthreads();
        for (int rr = 0; rr < 256 / 16; ++rr) {
            int row = wave * (256 / 16) + rr;
            float acc = 0.f;
            for (int w = 0; w < MASK_WORDS; ++w) {
                unsigned bits = mask[row * MASK_WORDS + w];
                while (bits) {
                    int b = __ffs(bits) - 1;
                    bits &= bits - 1;
                    acc += xg[(size_t)(w * 32 + b) * DIM + lane];
                }
            }
            float y = blds[lane];
            for (int k = 0; k < DIM; ++k) {
                float a = __shfl(acc, k, 64);
                y = fmaf(a, Wlds[k * DIM + lane], y);
            }
            vmax = fmaxf(vmax, y);
        }
    }
    red[wave * DIM + lane] = vmax;
    __syncthreads();
    if (tid < DIM) {
        float m = red[tid];
        #pragma unroll
        for (int w = 1; w < 16; ++w) m = fmaxf(m, red[w * DIM + tid]);
        pool[tid] = m;
    }
    __syncthreads();
    if (tid < DIM) {
        float h = b1[tid];
        for (int k = 0; k < DIM; ++k) h = fmaf(pool[k], w1[k * DIM + tid], h);
        hbuf[tid] = tanhf(h);
    }
    __syncthreads();
    if (tid < DIM) {
        float h2 = b2[tid];
        for (int k = 0; k < DIM; ++k) h2 = fmaf(hbuf[k], w2[k * DIM + tid], h2);
        h2 = tanhf(h2);
        red[tid] = h2 * w3[tid];
    }
    __syncthreads();
    if (tid == 0) {
        float v = b3[0];
        for (int k = 0; k < DIM; ++k) v += red[k];
        out[g] = v;
    }
}

extern "C" void kernel_launch(void* const* d_in, const int* in_sizes, int n_in,
                              void* d_out, int out_size, void* d_ws, size_t ws_size,
                              hipStream_t stream)
{
    const float* x      = (const float*)d_in[0];
    const int*   ei     = (const int*)d_in[1];   // int32 (harness converts)
    const float* weight = (const float*)d_in[4];
    const float* bias   = (const float*)d_in[5];
    const float* w1     = (const float*)d_in[6];
    const float* b1     = (const float*)d_in[7];
    const float* w2     = (const float*)d_in[8];
    const float* b2     = (const float*)d_in[9];
    const float* w3     = (const float*)d_in[10];
    const float* b3     = (const float*)d_in[11];
    float* out = (float*)d_out;

    const int E = in_sizes[1] / 2;

    // Tier A layout: [pooled 16KB | done 64B | segcnt 256KB | seg 16MB | xw 16MB]
    const size_t PL_BYTES  = (size_t)NGRAPH * DIM * 4 + 64;             // +done
    const size_t SC_BYTES  = (size_t)NBIN * NBUCKET * 2;                // 256 KB
    const size_t SEG_BYTES = (size_t)NBIN * NBUCKET * SEGCAP * 4;       // 16 MB
    const size_t XW_BYTES  = (size_t)NNODES * DIM * 4;                  // 16 MB
    const size_t need_A = PL_BYTES + SC_BYTES + SEG_BYTES + XW_BYTES;
    const size_t MASKW  = (size_t)NNODES * MASK_WORDS;
    const size_t need_B = MASKW * 4 + PL_BYTES;

    if (d_ws != nullptr && ws_size >= need_A) {
        char* base = (char*)d_ws;
        unsigned*       pooled_u = (unsigned*)base;
        unsigned*       done     = (unsigned*)(base + (size_t)NGRAPH * DIM * 4);
        unsigned short* segcnt   = (unsigned short*)(base + PL_BYTES);
        unsigned*       seg      = (unsigned*)(base + PL_BYTES + SC_BYTES);
        float*          xw       = (float*)(base + PL_BYTES + SC_BYTES + SEG_BYTES);

        bin_kernel<<<NBIN, 256, 0, stream>>>(ei, E, seg, segcnt, pooled_u, done);
        xw_kernel<<<NNODES / 64, 256, 0, stream>>>(x, weight, xw);
        agg_tiled_kernel<<<NBUCKET, 1024, 0, stream>>>(
            xw, bias, seg, segcnt, pooled_u, done,
            w1, b1, w2, b2, w3, b3, out);
    } else if (d_ws != nullptr && ws_size >= need_B) {
        unsigned* mask     = (unsigned*)d_ws;
        unsigned* pooled_u = mask + MASKW;
        clear_kernel<<<1024, 256, 0, stream>>>((uint4*)mask, (int)((MASKW * 4 + 16384) / 16));
        scatter_kernel<<<(E + 255) / 256, 256, 0, stream>>>(ei, mask, E);
        agg_kernel<<<NNODES / 64, 256, 0, stream>>>(x, weight, bias, mask, pooled_u);
        mlp_kernel<<<NGRAPH, DIM, 0, stream>>>(pooled_u, w1, b1, w2, b2, w3, b3, out);
    } else {
        fused_kernel<<<NGRAPH, 1024, 0, stream>>>(
            x, ei, E, weight, bias, w1, b1, w2, b2, w3, b3, out);
    }
}

// Round 9
// 92.582 us; speedup vs baseline: 1.3204x; 1.3204x over previous
//
#include <hip/hip_runtime.h>
#include <hip/hip_bf16.h>

// GraphConvPooling: y = (A @ x) @ W + b ; pooled = max_rows(y) ; MLP(tanh,tanh,lin)
// A is DEDUPLICATED 0/1 adjacency (.set semantics). Reassociated: y = A@(x@W)+b.
//
// Tier A (ws >= ~33MB): bin(+pooled/done clear) -> xw GEMM (XCD-swizzled)
//   -> agg_gather (LDS mask dedup -> padded lists -> 16-deep batched gather,
//      fused last-block MLP). Gather is latency-bound: lists padded to 8-aligned
//      pair-common length with sentinel 0 so EVERY batch issues 16 independent
//      loads (round-7's per-row tail loops dropped effective MLP to ~3.5).
// Tier B (ws >= ~8.4MB): round-3 proven bitmask path. Tier C: zero-ws fused.
//
// B=64 graphs, N=1024 nodes/graph, D=64. edge_index arrives as INT32.

#define NNODES 65536
#define NGRAPH 64
#define NLOCAL 1024
#define DIM 64
#define MASK_WORDS 32   // 1024 bits / 32
#define KMAX 64         // max deduped out-degree kept (P(deg>64) ~ e^-16)
#define CHUNK_ROWS 128  // dest rows per agg block / bucket
#define NBIN 256        // bin blocks
#define NBUCKET 512     // 64 graphs x 8 chunks of 128 rows
#define SEGCAP 32       // slots per (bin,bucket) segment: mean 8, P(>32)~1e-11

__device__ __forceinline__ unsigned f2ord(float f) {
    unsigned u = __float_as_uint(f);
    return (u & 0x80000000u) ? ~u : (u | 0x80000000u);
}
__device__ __forceinline__ float ord2f(unsigned u) {
    return (u & 0x80000000u) ? __uint_as_float(u & 0x7FFFFFFFu)
                             : __uint_as_float(~u);
}

__global__ __launch_bounds__(256) void clear_kernel(uint4* __restrict__ p, int n4)
{
    int i = blockIdx.x * 256 + threadIdx.x;
    int stride = gridDim.x * 256;
    uint4 z = {0u, 0u, 0u, 0u};
    for (; i < n4; i += stride) p[i] = z;
}

// Privatized binning: block b owns seg[b][bucket][SEGCAP] (128B, line-aligned,
// written ONLY by b -> plain stores, no global atomics). Also zeroes pooled+done.
// bucket = g*8 + (s_loc>>7). Payload = (s_loc<<10)|t_loc.
__global__ __launch_bounds__(256) void bin_kernel(
    const int* __restrict__ ei, int E,
    unsigned* __restrict__ seg, unsigned short* __restrict__ segcnt,
    unsigned* __restrict__ pooled_u, unsigned* __restrict__ done)
{
    __shared__ unsigned off[NBUCKET];
    int tid = threadIdx.x;
    off[tid] = 0u;
    off[tid + 256] = 0u;
    if (blockIdx.x < 16) pooled_u[blockIdx.x * 256 + tid] = 0u;  // folded clear
    if (blockIdx.x == 16 && tid == 0) *done = 0u;
    __syncthreads();
    int perblk = (E + NBIN - 1) / NBIN;
    int e0 = blockIdx.x * perblk;
    int e1 = min(e0 + perblk, E);
    unsigned* myseg = seg + (size_t)blockIdx.x * NBUCKET * SEGCAP;
    for (int e = e0 + tid; e < e1; e += 256) {
        int s = ei[e];
        int t = ei[E + e] & (NLOCAL - 1);
        int sl = s & (NLOCAL - 1);
        int bk = ((s >> 10) << 3) | (sl >> 7);
        unsigned slot = atomicAdd(&off[bk], 1u);       // LDS atomic
        if (slot < SEGCAP) myseg[bk * SEGCAP + slot] = (unsigned)((sl << 10) | t);
    }
    __syncthreads();
    unsigned c0 = off[tid], c1 = off[tid + 256];
    segcnt[blockIdx.x * NBUCKET + tid]       = (unsigned short)(c0 < SEGCAP ? c0 : SEGCAP);
    segcnt[blockIdx.x * NBUCKET + tid + 256] = (unsigned short)(c1 < SEGCAP ? c1 : SEGCAP);
}

// xw = x @ W, XCD-swizzled so graph g's rows are written on g%8's XCD
// (same XCD agg's blocks for g run on).
__global__ __launch_bounds__(256) void xw_kernel(
    const float* __restrict__ x, const float* __restrict__ W,
    float* __restrict__ xw)
{
    __shared__ float4 xlds[64 * 16];
    int tid = threadIdx.x;
    int b = blockIdx.x;                  // 1024 blocks
    int xcd = b & 7, idx = b >> 3;       // idx 0..127
    int g = ((idx >> 4) << 3) | xcd;     // g%8 == xcd
    int sub = idx & 15;                  // 16 x 64-row sub-blocks per graph
    int row0 = (g << 10) + (sub << 6);

    const float4* xg4 = (const float4*)(x + (size_t)row0 * DIM);
    for (int i = tid; i < 64 * 16; i += 256) xlds[i] = xg4[i];
    int col = tid & 63;
    int rg  = tid >> 6;
    float w[64];
    #pragma unroll
    for (int k = 0; k < 64; ++k) w[k] = W[k * DIM + col];
    __syncthreads();
    #pragma unroll
    for (int rr = 0; rr < 16; ++rr) {
        int row = rg * 16 + rr;
        float acc = 0.f;
        #pragma unroll
        for (int k4 = 0; k4 < 16; ++k4) {
            float4 xv = xlds[row * 16 + k4];
            acc = fmaf(xv.x, w[4 * k4 + 0], acc);
            acc = fmaf(xv.y, w[4 * k4 + 1], acc);
            acc = fmaf(xv.z, w[4 * k4 + 2], acc);
            acc = fmaf(xv.w, w[4 * k4 + 3], acc);
        }
        xw[(size_t)(row0 + row) * DIM + col] = acc;
    }
}

// One block per (graph, 128-row dest chunk), 1024 thr (16 waves x 8 rows).
// Row-pair gather with fixed 8+8 batches: 16 loads in flight, no tails.
// Last block (device atomic counter) runs the MLP.
__global__ __launch_bounds__(1024, 8) void agg_gather_kernel(
    const float* __restrict__ xw, const float* __restrict__ bias,
    const unsigned* __restrict__ seg, const unsigned short* __restrict__ segcnt,
    unsigned* __restrict__ pooled_u, unsigned* __restrict__ done,
    const float* __restrict__ w1, const float* __restrict__ b1,
    const float* __restrict__ w2, const float* __restrict__ b2,
    const float* __restrict__ w3, const float* __restrict__ b3,
    float* __restrict__ out)
{
    __shared__ unsigned mask[CHUNK_ROWS * MASK_WORDS];   // 16KB; becomes lists
    __shared__ float red[16 * DIM];                      // 4KB
    __shared__ unsigned lastflag;

    int tid = threadIdx.x;
    int lane = tid & 63, wave = tid >> 6;
    int b = blockIdx.x;
    int g = ((b >> 6) << 3) | (b & 7);   // g%8 == blockIdx%8 -> XCD locality
    int chunk = (b >> 3) & 7;
    int bk = (g << 3) | chunk;

    for (int i = tid; i < CHUNK_ROWS * MASK_WORDS; i += 1024) mask[i] = 0u;
    __syncthreads();

    // drain all bins' segments for this bucket into the LDS dedup mask
    for (int idx0 = tid; idx0 < NBIN * SEGCAP; idx0 += 1024) {
        int sb = idx0 >> 5;
        int sl = idx0 & 31;
        int n = segcnt[sb * NBUCKET + bk];
        if (sl < n) {
            unsigned pk = seg[((size_t)sb * NBUCKET + bk) * SEGCAP + sl];
            int r = (pk >> 10) & (CHUNK_ROWS - 1);
            int t = pk & (NLOCAL - 1);
            atomicOr(&mask[r * MASK_WORDS + (t >> 5)], 1u << (t & 31));
        }
    }
    __syncthreads();

    // extract sorted u16 lists in place (pairs, half-wave per row; wave-local),
    // then pad both rows of each pair to the pair-common 8-aligned end with 0
    // (sentinel -> graph row 0, one L1-hot line; masked out in the gather).
    unsigned short* lists = (unsigned short*)mask;
    int cc[8];
    #pragma unroll
    for (int i = 0; i < 8; i += 2) {
        int rowa = wave * 8 + i;
        int myrow = rowa + ((lane >> 5) & 1);
        unsigned bits = mask[myrow * MASK_WORDS + (lane & 31)];
        int c = __popc(bits);
        int inc = c;
        #pragma unroll
        for (int d = 1; d < 32; d <<= 1) {
            int v = __shfl_up(inc, d, 32);
            if ((lane & 31) >= d) inc += v;
        }
        int off = inc - c;
        unsigned short* lr = lists + myrow * KMAX;
        while (bits) {
            int bb = __ffs(bits) - 1;
            bits &= bits - 1;
            if (off < KMAX) lr[off] = (unsigned short)((lane & 31) * 32 + bb);
            ++off;
        }
        int cca = __shfl(inc, 31, 64);
        int ccb = __shfl(inc, 63, 64);
        cca = cca < KMAX ? cca : KMAX;
        ccb = ccb < KMAX ? ccb : KMAX;
        cc[i] = cca; cc[i + 1] = ccb;
        int pe = ((cca > ccb ? cca : ccb) + 7) & ~7;
        int cme = (lane < 32) ? cca : ccb;
        int l5 = lane & 31;
        for (int p = cme + l5; p < pe; p += 32) lr[p] = 0;
    }

    const float* xwg = xw + ((size_t)g << 10) * DIM;
    float bv = bias[lane];
    float vmax = -INFINITY;

    // gather: row pairs, fixed 8+8 batches, validity folded into fmaf masks
    #pragma unroll
    for (int i = 0; i < 8; i += 2) {
        int rowA = wave * 8 + i;
        const unsigned* lA = (const unsigned*)(lists + rowA * KMAX);
        const unsigned* lB = (const unsigned*)(lists + (rowA + 1) * KMAX);
        int cA = cc[i], cB = cc[i + 1];
        int pe = ((cA > cB ? cA : cB) + 7) & ~7;
        float a0 = 0.f, a1 = 0.f, a2 = 0.f, a3 = 0.f;
        float b0 = 0.f, b1_ = 0.f, b2_ = 0.f, b3_ = 0.f;
        for (int j = 0; j < pe; j += 8) {
            int q = j >> 1;
            unsigned wA0 = lA[q], wA1 = lA[q + 1], wA2 = lA[q + 2], wA3 = lA[q + 3];
            unsigned wB0 = lB[q], wB1 = lB[q + 1], wB2 = lB[q + 2], wB3 = lB[q + 3];
            float vA0 = xwg[(wA0 & 1023u) * DIM + lane];
            float vA1 = xwg[((wA0 >> 16) & 1023u) * DIM + lane];
            float vA2 = xwg[(wA1 & 1023u) * DIM + lane];
            float vA3 = xwg[((wA1 >> 16) & 1023u) * DIM + lane];
            float vA4 = xwg[(wA2 & 1023u) * DIM + lane];
            float vA5 = xwg[((wA2 >> 16) & 1023u) * DIM + lane];
            float vA6 = xwg[(wA3 & 1023u) * DIM + lane];
            float vA7 = xwg[((wA3 >> 16) & 1023u) * DIM + lane];
            float vB0 = xwg[(wB0 & 1023u) * DIM + lane];
            float vB1 = xwg[((wB0 >> 16) & 1023u) * DIM + lane];
            float vB2 = xwg[(wB1 & 1023u) * DIM + lane];
            float vB3 = xwg[((wB1 >> 16) & 1023u) * DIM + lane];
            float vB4 = xwg[(wB2 & 1023u) * DIM + lane];
            float vB5 = xwg[((wB2 >> 16) & 1023u) * DIM + lane];
            float vB6 = xwg[(wB3 & 1023u) * DIM + lane];
            float vB7 = xwg[((wB3 >> 16) & 1023u) * DIM + lane];
            a0 = fmaf((j + 0) < cA ? 1.f : 0.f, vA0, a0);
            a1 = fmaf((j + 1) < cA ? 1.f : 0.f, vA1, a1);
            a2 = fmaf((j + 2) < cA ? 1.f : 0.f, vA2, a2);
            a3 = fmaf((j + 3) < cA ? 1.f : 0.f, vA3, a3);
            a0 = fmaf((j + 4) < cA ? 1.f : 0.f, vA4, a0);
            a1 = fmaf((j + 5) < cA ? 1.f : 0.f, vA5, a1);
            a2 = fmaf((j + 6) < cA ? 1.f : 0.f, vA6, a2);
            a3 = fmaf((j + 7) < cA ? 1.f : 0.f, vA7, a3);
            b0 = fmaf((j + 0) < cB ? 1.f : 0.f, vB0, b0);
            b1_ = fmaf((j + 1) < cB ? 1.f : 0.f, vB1, b1_);
            b2_ = fmaf((j + 2) < cB ? 1.f : 0.f, vB2, b2_);
            b3_ = fmaf((j + 3) < cB ? 1.f : 0.f, vB3, b3_);
            b0 = fmaf((j + 4) < cB ? 1.f : 0.f, vB4, b0);
            b1_ = fmaf((j + 5) < cB ? 1.f : 0.f, vB5, b1_);
            b2_ = fmaf((j + 6) < cB ? 1.f : 0.f, vB6, b2_);
            b3_ = fmaf((j + 7) < cB ? 1.f : 0.f, vB7, b3_);
        }
        vmax = fmaxf(vmax, ((a0 + a1) + (a2 + a3)) + bv);
        vmax = fmaxf(vmax, ((b0 + b1_) + (b2_ + b3_)) + bv);
    }

    red[wave * DIM + lane] = vmax;
    __syncthreads();
    if (wave == 0) {
        float m = red[lane];
        #pragma unroll
        for (int w = 1; w < 16; ++w) m = fmaxf(m, red[w * DIM + lane]);
        atomicMax(&pooled_u[g * DIM + lane], f2ord(m));
    }
    // ---- last block runs the MLP (pooled complete; output deterministic) ----
    if (tid == 0) {
        __threadfence();
        unsigned v = atomicAdd(done, 1u);
        lastflag = (v == NBUCKET - 1) ? 1u : 0u;
    }
    __syncthreads();
    if (lastflag) {
        for (int gg = 0; gg < 4; ++gg) {
            int g2 = wave * 4 + gg;
            float pl = ord2f(atomicOr(&pooled_u[g2 * DIM + lane], 0u));
            float h = b1[lane];
            for (int k2 = 0; k2 < 64; ++k2) {
                float a = __shfl(pl, k2, 64);
                h = fmaf(a, w1[k2 * DIM + lane], h);
            }
            h = tanhf(h);
            float h2 = b2[lane];
            for (int k2 = 0; k2 < 64; ++k2) {
                float a = __shfl(h, k2, 64);
                h2 = fmaf(a, w2[k2 * DIM + lane], h2);
            }
            h2 = tanhf(h2);
            float v2 = h2 * w3[lane];
            #pragma unroll
            for (int o = 32; o; o >>= 1) v2 += __shfl_down(v2, o, 64);
            if (lane == 0) out[g2] = v2 + b3[0];
        }
    }
}

__global__ __launch_bounds__(64) void mlp_kernel(
    const unsigned* __restrict__ pooled_u,
    const float* __restrict__ w1, const float* __restrict__ b1,
    const float* __restrict__ w2, const float* __restrict__ b2,
    const float* __restrict__ w3, const float* __restrict__ b3,
    float* __restrict__ out)
{
    __shared__ float buf[DIM];
    __shared__ float buf2[DIM];
    int g = blockIdx.x, l = threadIdx.x;
    buf[l] = ord2f(pooled_u[g * DIM + l]);
    __syncthreads();
    float h = b1[l];
    for (int k = 0; k < DIM; ++k) h = fmaf(buf[k], w1[k * DIM + l], h);
    buf2[l] = tanhf(h);
    __syncthreads();
    float h2 = b2[l];
    for (int k = 0; k < DIM; ++k) h2 = fmaf(buf2[k], w2[k * DIM + l], h2);
    h2 = tanhf(h2);
    float v = h2 * w3[l];
    #pragma unroll
    for (int off = 32; off; off >>= 1) v += __shfl_down(v, off, 64);
    if (l == 0) out[g] = v + b3[0];
}

// ---- Tier B (round-3 proven): global bitmask + ffs + shfl matvec ----
__global__ __launch_bounds__(256) void scatter_kernel(
    const int* __restrict__ ei, unsigned* __restrict__ mask, int E)
{
    int e = blockIdx.x * 256 + threadIdx.x;
    if (e >= E) return;
    int start = ei[e];
    int col   = ei[E + e] & (NLOCAL - 1);
    atomicOr(&mask[(size_t)start * MASK_WORDS + (col >> 5)], 1u << (col & 31));
}

__global__ __launch_bounds__(256) void agg_kernel(
    const float* __restrict__ x, const float* __restrict__ weight,
    const float* __restrict__ bias, const unsigned* __restrict__ mask,
    unsigned* __restrict__ pooled_u)
{
    __shared__ float Wlds[DIM * DIM];
    __shared__ float blds[DIM];
    int tid = threadIdx.x;
    for (int i = tid; i < DIM * DIM; i += 256) Wlds[i] = weight[i];
    if (tid < DIM) blds[tid] = bias[tid];
    __syncthreads();
    int lane = tid & 63;
    int wave = tid >> 6;
    int rowbase = blockIdx.x * 64 + wave * 16;
    int g = rowbase >> 10;
    const float* xg = x + ((size_t)g << 10) * DIM;
    float vmax = -INFINITY;
    for (int rr = 0; rr < 16; ++rr) {
        int row = rowbase + rr;
        const unsigned* mrow = mask + (size_t)row * MASK_WORDS;
        float acc = 0.f;
        for (int w = 0; w < MASK_WORDS; ++w) {
            unsigned bits = mrow[w];
            while (bits) {
                int b = __ffs(bits) - 1;
                bits &= bits - 1;
                acc += xg[(size_t)(w * 32 + b) * DIM + lane];
            }
        }
        float y = blds[lane];
        for (int k = 0; k < DIM; ++k) {
            float a = __shfl(acc, k, 64);
            y = fmaf(a, Wlds[k * DIM + lane], y);
        }
        vmax = fmaxf(vmax, y);
    }
    atomicMax(&pooled_u[g * DIM + lane], f2ord(vmax));
}

// ---- Tier C: fused zero-workspace fallback ----
__global__ __launch_bounds__(1024) void fused_kernel(
    const float* __restrict__ x, const int* __restrict__ ei, int E,
    const float* __restrict__ weight, const float* __restrict__ bias,
    const float* __restrict__ w1, const float* __restrict__ b1,
    const float* __restrict__ w2, const float* __restrict__ b2,
    const float* __restrict__ w3, const float* __restrict__ b3,
    float* __restrict__ out)
{
    __shared__ unsigned mask[256 * MASK_WORDS];
    __shared__ float Wlds[DIM * DIM];
    __shared__ float blds[DIM];
    __shared__ float red[16 * DIM];
    __shared__ float pool[DIM];
    __shared__ float hbuf[DIM];
    int tid = threadIdx.x;
    int g = blockIdx.x;
    int lane = tid & 63;
    int wave = tid >> 6;
    const float* xg = x + ((size_t)g << 10) * DIM;
    for (int i = tid; i < DIM * DIM; i += 1024) Wlds[i] = weight[i];
    if (tid < DIM) blds[tid] = bias[tid];
    float vmax = -INFINITY;
    for (int chunk = 0; chunk < NLOCAL / 256; ++chunk) {
        int row0 = chunk * 256;
        __syncthreads();
        for (int i = tid; i < 256 * MASK_WORDS; i += 1024) mask[i] = 0u;
        __syncthreads();
        int lo = (g << 10) + row0, hi = lo + 256;
        for (int e = tid; e < E; e += 1024) {
            int s = ei[e];
            if (s >= lo && s < hi) {
                int t = ei[E + e] & (NLOCAL - 1);
                atomicOr(&mask[(s - lo) * MASK_WORDS + (t >> 5)], 1u << (t & 31));
            }
        }
        __syncthreads();
        for (int rr = 0; rr < 256 / 16; ++rr) {
            int row = wave * (256 / 16) + rr;
            float acc = 0.f;
            for (int w = 0; w < MASK_WORDS; ++w) {
                unsigned bits = mask[row * MASK_WORDS + w];
                while (bits) {
                    int b = __ffs(bits) - 1;
                    bits &= bits - 1;
                    acc += xg[(size_t)(w * 32 + b) * DIM + lane];
                }
            }
            float y = blds[lane];
            for (int k = 0; k < DIM; ++k) {
                float a = __shfl(acc, k, 64);
                y = fmaf(a, Wlds[k * DIM + lane], y);
            }
            vmax = fmaxf(vmax, y);
        }
    }
    red[wave * DIM + lane] = vmax;
    __syncthreads();
    if (tid < DIM) {
        float m = red[tid];
        #pragma unroll
        for (int w = 1; w < 16; ++w) m = fmaxf(m, red[w * DIM + tid]);
        pool[tid] = m;
    }
    __syncthreads();
    if (tid < DIM) {
        float h = b1[tid];
        for (int k = 0; k < DIM; ++k) h = fmaf(pool[k], w1[k * DIM + tid], h);
        hbuf[tid] = tanhf(h);
    }
    __syncthreads();
    if (tid < DIM) {
        float h2 = b2[tid];
        for (int k = 0; k < DIM; ++k) h2 = fmaf(hbuf[k], w2[k * DIM + tid], h2);
        h2 = tanhf(h2);
        red[tid] = h2 * w3[tid];
    }
    __syncthreads();
    if (tid == 0) {
        float v = b3[0];
        for (int k = 0; k < DIM; ++k) v += red[k];
        out[g] = v;
    }
}

extern "C" void kernel_launch(void* const* d_in, const int* in_sizes, int n_in,
                              void* d_out, int out_size, void* d_ws, size_t ws_size,
                              hipStream_t stream)
{
    const float* x      = (const float*)d_in[0];
    const int*   ei     = (const int*)d_in[1];   // int32 (harness converts)
    const float* weight = (const float*)d_in[4];
    const float* bias   = (const float*)d_in[5];
    const float* w1     = (const float*)d_in[6];
    const float* b1     = (const float*)d_in[7];
    const float* w2     = (const float*)d_in[8];
    const float* b2     = (const float*)d_in[9];
    const float* w3     = (const float*)d_in[10];
    const float* b3     = (const float*)d_in[11];
    float* out = (float*)d_out;

    const int E = in_sizes[1] / 2;

    // Tier A layout: [pooled 16KB | done 64B | segcnt 256KB | seg 16MB | xw 16MB]
    const size_t PL_BYTES  = (size_t)NGRAPH * DIM * 4 + 64;             // +done
    const size_t SC_BYTES  = (size_t)NBIN * NBUCKET * 2;                // 256 KB
    const size_t SEG_BYTES = (size_t)NBIN * NBUCKET * SEGCAP * 4;       // 16 MB
    const size_t XW_BYTES  = (size_t)NNODES * DIM * 4;                  // 16 MB
    const size_t need_A = PL_BYTES + SC_BYTES + SEG_BYTES + XW_BYTES;
    const size_t MASKW  = (size_t)NNODES * MASK_WORDS;
    const size_t need_B = MASKW * 4 + PL_BYTES;

    if (d_ws != nullptr && ws_size >= need_A) {
        char* base = (char*)d_ws;
        unsigned*       pooled_u = (unsigned*)base;
        unsigned*       done     = (unsigned*)(base + (size_t)NGRAPH * DIM * 4);
        unsigned short* segcnt   = (unsigned short*)(base + PL_BYTES);
        unsigned*       seg      = (unsigned*)(base + PL_BYTES + SC_BYTES);
        float*          xw       = (float*)(base + PL_BYTES + SC_BYTES + SEG_BYTES);

        bin_kernel<<<NBIN, 256, 0, stream>>>(ei, E, seg, segcnt, pooled_u, done);
        xw_kernel<<<NNODES / 64, 256, 0, stream>>>(x, weight, xw);
        agg_gather_kernel<<<NBUCKET, 1024, 0, stream>>>(
            xw, bias, seg, segcnt, pooled_u, done,
            w1, b1, w2, b2, w3, b3, out);
    } else if (d_ws != nullptr && ws_size >= need_B) {
        unsigned* mask     = (unsigned*)d_ws;
        unsigned* pooled_u = mask + MASKW;
        clear_kernel<<<1024, 256, 0, stream>>>((uint4*)mask, (int)((MASKW * 4 + 16384) / 16));
        scatter_kernel<<<(E + 255) / 256, 256, 0, stream>>>(ei, mask, E);
        agg_kernel<<<NNODES / 64, 256, 0, stream>>>(x, weight, bias, mask, pooled_u);
        mlp_kernel<<<NGRAPH, DIM, 0, stream>>>(pooled_u, w1, b1, w2, b2, w3, b3, out);
    } else {
        fused_kernel<<<NGRAPH, 1024, 0, stream>>>(
            x, ei, E, weight, bias, w1, b1, w2, b2, w3, b3, out);
    }
}

// Round 10
// 89.909 us; speedup vs baseline: 1.3596x; 1.0297x over previous
//
#include <hip/hip_runtime.h>
#include <hip/hip_bf16.h>

// GraphConvPooling: y = (A @ x) @ W + b ; pooled = max_rows(y) ; MLP(tanh,tanh,lin)
// A is DEDUPLICATED 0/1 adjacency (.set semantics). Reassociated: y = A@(x@W)+b.
//
// Tier A (ws >= ~33MB): bin(+pooled/done clear) -> xw GEMM (XCD-swizzled)
//   -> agg_gather: LDS mask dedup -> u16 lists (+rowcnt LDS) -> FLOAT4 gather
//      (16 lanes x 16B per neighbor row, 4 dest rows per instruction: 1/4 the
//      gather instructions of the scalar version -- rounds 4-9 showed the wall
//      is gather-instructions-per-wave-window, not bytes) -> fused MLP.
// Tier B (ws >= ~8.4MB): round-3 proven bitmask path. Tier C: zero-ws fused.
//
// B=64 graphs, N=1024 nodes/graph, D=64. edge_index arrives as INT32.

#define NNODES 65536
#define NGRAPH 64
#define NLOCAL 1024
#define DIM 64
#define MASK_WORDS 32   // 1024 bits / 32
#define KMAX 64         // max deduped out-degree kept (P(deg>64) ~ e^-16)
#define CHUNK_ROWS 128  // dest rows per agg block / bucket
#define NBIN 256        // bin blocks
#define NBUCKET 512     // 64 graphs x 8 chunks of 128 rows
#define SEGCAP 32       // slots per (bin,bucket) segment: mean 8, P(>32)~1e-11

__device__ __forceinline__ unsigned f2ord(float f) {
    unsigned u = __float_as_uint(f);
    return (u & 0x80000000u) ? ~u : (u | 0x80000000u);
}
__device__ __forceinline__ float ord2f(unsigned u) {
    return (u & 0x80000000u) ? __uint_as_float(u & 0x7FFFFFFFu)
                             : __uint_as_float(~u);
}

__global__ __launch_bounds__(256) void clear_kernel(uint4* __restrict__ p, int n4)
{
    int i = blockIdx.x * 256 + threadIdx.x;
    int stride = gridDim.x * 256;
    uint4 z = {0u, 0u, 0u, 0u};
    for (; i < n4; i += stride) p[i] = z;
}

// Privatized binning: block b owns seg[b][bucket][SEGCAP] (128B, line-aligned,
// written ONLY by b -> plain stores, no global atomics). Also zeroes pooled+done.
__global__ __launch_bounds__(256) void bin_kernel(
    const int* __restrict__ ei, int E,
    unsigned* __restrict__ seg, unsigned short* __restrict__ segcnt,
    unsigned* __restrict__ pooled_u, unsigned* __restrict__ done)
{
    __shared__ unsigned off[NBUCKET];
    int tid = threadIdx.x;
    off[tid] = 0u;
    off[tid + 256] = 0u;
    if (blockIdx.x < 16) pooled_u[blockIdx.x * 256 + tid] = 0u;  // folded clear
    if (blockIdx.x == 16 && tid == 0) *done = 0u;
    __syncthreads();
    int perblk = (E + NBIN - 1) / NBIN;
    int e0 = blockIdx.x * perblk;
    int e1 = min(e0 + perblk, E);
    unsigned* myseg = seg + (size_t)blockIdx.x * NBUCKET * SEGCAP;
    for (int e = e0 + tid; e < e1; e += 256) {
        int s = ei[e];
        int t = ei[E + e] & (NLOCAL - 1);
        int sl = s & (NLOCAL - 1);
        int bk = ((s >> 10) << 3) | (sl >> 7);
        unsigned slot = atomicAdd(&off[bk], 1u);       // LDS atomic
        if (slot < SEGCAP) myseg[bk * SEGCAP + slot] = (unsigned)((sl << 10) | t);
    }
    __syncthreads();
    unsigned c0 = off[tid], c1 = off[tid + 256];
    segcnt[blockIdx.x * NBUCKET + tid]       = (unsigned short)(c0 < SEGCAP ? c0 : SEGCAP);
    segcnt[blockIdx.x * NBUCKET + tid + 256] = (unsigned short)(c1 < SEGCAP ? c1 : SEGCAP);
}

// xw = x @ W, XCD-swizzled so graph g's rows are produced on g%8's XCD.
__global__ __launch_bounds__(256) void xw_kernel(
    const float* __restrict__ x, const float* __restrict__ W,
    float* __restrict__ xw)
{
    __shared__ float4 xlds[64 * 16];
    int tid = threadIdx.x;
    int b = blockIdx.x;                  // 1024 blocks
    int xcd = b & 7, idx = b >> 3;
    int g = ((idx >> 4) << 3) | xcd;     // g%8 == xcd
    int sub = idx & 15;
    int row0 = (g << 10) + (sub << 6);

    const float4* xg4 = (const float4*)(x + (size_t)row0 * DIM);
    for (int i = tid; i < 64 * 16; i += 256) xlds[i] = xg4[i];
    int col = tid & 63;
    int rg  = tid >> 6;
    float w[64];
    #pragma unroll
    for (int k = 0; k < 64; ++k) w[k] = W[k * DIM + col];
    __syncthreads();
    #pragma unroll
    for (int rr = 0; rr < 16; ++rr) {
        int row = rg * 16 + rr;
        float acc = 0.f;
        #pragma unroll
        for (int k4 = 0; k4 < 16; ++k4) {
            float4 xv = xlds[row * 16 + k4];
            acc = fmaf(xv.x, w[4 * k4 + 0], acc);
            acc = fmaf(xv.y, w[4 * k4 + 1], acc);
            acc = fmaf(xv.z, w[4 * k4 + 2], acc);
            acc = fmaf(xv.w, w[4 * k4 + 3], acc);
        }
        xw[(size_t)(row0 + row) * DIM + col] = acc;
    }
}

// One block per (graph, 128-row dest chunk), 1024 thr (16 waves x 8 rows).
// FLOAT4 gather: lane = 16*p + q; group p owns a dest row, q owns col-quad.
// Last block (device atomic counter) runs the MLP.
__global__ __launch_bounds__(1024, 8) void agg_gather_kernel(
    const float* __restrict__ xw, const float* __restrict__ bias,
    const unsigned* __restrict__ seg, const unsigned short* __restrict__ segcnt,
    unsigned* __restrict__ pooled_u, unsigned* __restrict__ done,
    const float* __restrict__ w1, const float* __restrict__ b1,
    const float* __restrict__ w2, const float* __restrict__ b2,
    const float* __restrict__ w3, const float* __restrict__ b3,
    float* __restrict__ out)
{
    __shared__ unsigned mask[CHUNK_ROWS * MASK_WORDS];   // 16KB; becomes lists
    __shared__ unsigned short rowcnt[CHUNK_ROWS];        // 256B (wave-local use)
    __shared__ float red[16 * DIM];                      // 4KB
    __shared__ unsigned lastflag;

    int tid = threadIdx.x;
    int lane = tid & 63, wave = tid >> 6;
    int b = blockIdx.x;
    int g = ((b >> 6) << 3) | (b & 7);   // g%8 == blockIdx%8 -> XCD locality
    int chunk = (b >> 3) & 7;
    int bk = (g << 3) | chunk;

    for (int i = tid; i < CHUNK_ROWS * MASK_WORDS; i += 1024) mask[i] = 0u;
    __syncthreads();

    // drain all bins' segments for this bucket into the LDS dedup mask
    for (int idx0 = tid; idx0 < NBIN * SEGCAP; idx0 += 1024) {
        int sb = idx0 >> 5;
        int sl = idx0 & 31;
        int n = segcnt[sb * NBUCKET + bk];
        if (sl < n) {
            unsigned pk = seg[((size_t)sb * NBUCKET + bk) * SEGCAP + sl];
            int r = (pk >> 10) & (CHUNK_ROWS - 1);
            int t = pk & (NLOCAL - 1);
            atomicOr(&mask[r * MASK_WORDS + (t >> 5)], 1u << (t & 31));
        }
    }
    __syncthreads();

    // ---- extract sorted u16 lists in place (pairs, half-wave per row) ----
    unsigned short* lists = (unsigned short*)mask;
    #pragma unroll
    for (int i = 0; i < 8; i += 2) {
        int rowa = wave * 8 + i;
        int myrow = rowa + ((lane >> 5) & 1);
        unsigned bits = mask[myrow * MASK_WORDS + (lane & 31)];
        int c = __popc(bits);
        int inc = c;
        #pragma unroll
        for (int d = 1; d < 32; d <<= 1) {
            int v = __shfl_up(inc, d, 32);
            if ((lane & 31) >= d) inc += v;
        }
        int off = inc - c;
        unsigned short* lr = lists + myrow * KMAX;
        while (bits) {
            int bb = __ffs(bits) - 1;
            bits &= bits - 1;
            if (off < KMAX) lr[off] = (unsigned short)((lane & 31) * 32 + bb);
            ++off;
        }
        if ((lane & 31) == 31)
            rowcnt[myrow] = (unsigned short)(inc < KMAX ? inc : KMAX);
    }
    // rowcnt/lists wave-local from here on: no barrier needed.

    int q = lane & 15, p = lane >> 4;

    // ---- pad each 4-row set to its common 4-aligned length with sentinel 0 ----
    #pragma unroll
    for (int s = 0; s < 2; ++s) {
        int r0 = wave * 8 + s * 4;
        int c0 = rowcnt[r0], c1 = rowcnt[r0 + 1];
        int c2 = rowcnt[r0 + 2], c3 = rowcnt[r0 + 3];
        int pe = max(max(c0, c1), max(c2, c3));
        pe = (pe + 3) & ~3;
        int r = r0 + p;                       // group p pads its row
        int cr = rowcnt[r];
        unsigned short* lr = lists + r * KMAX;
        for (int j = cr + q; j < pe; j += 16) lr[j] = 0;
    }

    // ---- float4 gather: 2 sets x ~22 wave-instructions, unroll-4 deep ----
    const float4* xwg4 = (const float4*)(xw + (((size_t)g) << 10) * DIM);
    float4 bias4 = ((const float4*)bias)[q];
    float4 vmax4 = make_float4(-INFINITY, -INFINITY, -INFINITY, -INFINITY);

    #pragma unroll
    for (int s = 0; s < 2; ++s) {
        int r0 = wave * 8 + s * 4;
        int r = r0 + p;
        int ccl = rowcnt[r];
        // wave-uniform padded end (matches padding step)
        int pm = ccl;
        pm = max(pm, __shfl_xor(pm, 16, 64));
        pm = max(pm, __shfl_xor(pm, 32, 64));
        int pe = (pm + 3) & ~3;
        const unsigned short* lr = lists + r * KMAX;
        float4 acc = make_float4(0.f, 0.f, 0.f, 0.f);
        for (int j = 0; j < pe; j += 4) {
            #pragma unroll
            for (int u = 0; u < 4; ++u) {
                int t = lr[j + u] & 1023;            // sentinel-safe
                float m = (j + u) < ccl ? 1.f : 0.f;
                float4 v = xwg4[t * 16 + q];         // 16B/lane, 4 rows/instr
                acc.x = fmaf(m, v.x, acc.x);
                acc.y = fmaf(m, v.y, acc.y);
                acc.z = fmaf(m, v.z, acc.z);
                acc.w = fmaf(m, v.w, acc.w);
            }
        }
        vmax4.x = fmaxf(vmax4.x, acc.x + bias4.x);
        vmax4.y = fmaxf(vmax4.y, acc.y + bias4.y);
        vmax4.z = fmaxf(vmax4.z, acc.z + bias4.z);
        vmax4.w = fmaxf(vmax4.w, acc.w + bias4.w);
    }

    // cross-group (p) max: lanes differing in bits 4,5
    vmax4.x = fmaxf(vmax4.x, __shfl_xor(vmax4.x, 16, 64));
    vmax4.y = fmaxf(vmax4.y, __shfl_xor(vmax4.y, 16, 64));
    vmax4.z = fmaxf(vmax4.z, __shfl_xor(vmax4.z, 16, 64));
    vmax4.w = fmaxf(vmax4.w, __shfl_xor(vmax4.w, 16, 64));
    vmax4.x = fmaxf(vmax4.x, __shfl_xor(vmax4.x, 32, 64));
    vmax4.y = fmaxf(vmax4.y, __shfl_xor(vmax4.y, 32, 64));
    vmax4.z = fmaxf(vmax4.z, __shfl_xor(vmax4.z, 32, 64));
    vmax4.w = fmaxf(vmax4.w, __shfl_xor(vmax4.w, 32, 64));
    if (p == 0) ((float4*)red)[wave * 16 + q] = vmax4;   // cols 4q..4q+3
    __syncthreads();

    if (wave == 0) {
        float m = red[lane];
        #pragma unroll
        for (int w = 1; w < 16; ++w) m = fmaxf(m, red[w * DIM + lane]);
        atomicMax(&pooled_u[g * DIM + lane], f2ord(m));
    }
    // ---- last block runs the MLP (pooled complete; output deterministic) ----
    if (tid == 0) {
        __threadfence();
        unsigned v = atomicAdd(done, 1u);
        lastflag = (v == NBUCKET - 1) ? 1u : 0u;
    }
    __syncthreads();
    if (lastflag) {
        for (int gg = 0; gg < 4; ++gg) {
            int g2 = wave * 4 + gg;
            float pl = ord2f(atomicOr(&pooled_u[g2 * DIM + lane], 0u));
            float h = b1[lane];
            for (int k2 = 0; k2 < 64; ++k2) {
                float a = __shfl(pl, k2, 64);
                h = fmaf(a, w1[k2 * DIM + lane], h);
            }
            h = tanhf(h);
            float h2 = b2[lane];
            for (int k2 = 0; k2 < 64; ++k2) {
                float a = __shfl(h, k2, 64);
                h2 = fmaf(a, w2[k2 * DIM + lane], h2);
            }
            h2 = tanhf(h2);
            float v2 = h2 * w3[lane];
            #pragma unroll
            for (int o = 32; o; o >>= 1) v2 += __shfl_down(v2, o, 64);
            if (lane == 0) out[g2] = v2 + b3[0];
        }
    }
}

__global__ __launch_bounds__(64) void mlp_kernel(
    const unsigned* __restrict__ pooled_u,
    const float* __restrict__ w1, const float* __restrict__ b1,
    const float* __restrict__ w2, const float* __restrict__ b2,
    const float* __restrict__ w3, const float* __restrict__ b3,
    float* __restrict__ out)
{
    __shared__ float buf[DIM];
    __shared__ float buf2[DIM];
    int g = blockIdx.x, l = threadIdx.x;
    buf[l] = ord2f(pooled_u[g * DIM + l]);
    __syncthreads();
    float h = b1[l];
    for (int k = 0; k < DIM; ++k) h = fmaf(buf[k], w1[k * DIM + l], h);
    buf2[l] = tanhf(h);
    __syncthreads();
    float h2 = b2[l];
    for (int k = 0; k < DIM; ++k) h2 = fmaf(buf2[k], w2[k * DIM + l], h2);
    h2 = tanhf(h2);
    float v = h2 * w3[l];
    #pragma unroll
    for (int off = 32; off; off >>= 1) v += __shfl_down(v, off, 64);
    if (l == 0) out[g] = v + b3[0];
}

// ---- Tier B (round-3 proven): global bitmask + ffs + shfl matvec ----
__global__ __launch_bounds__(256) void scatter_kernel(
    const int* __restrict__ ei, unsigned* __restrict__ mask, int E)
{
    int e = blockIdx.x * 256 + threadIdx.x;
    if (e >= E) return;
    int start = ei[e];
    int col   = ei[E + e] & (NLOCAL - 1);
    atomicOr(&mask[(size_t)start * MASK_WORDS + (col >> 5)], 1u << (col & 31));
}

__global__ __launch_bounds__(256) void agg_kernel(
    const float* __restrict__ x, const float* __restrict__ weight,
    const float* __restrict__ bias, const unsigned* __restrict__ mask,
    unsigned* __restrict__ pooled_u)
{
    __shared__ float Wlds[DIM * DIM];
    __shared__ float blds[DIM];
    int tid = threadIdx.x;
    for (int i = tid; i < DIM * DIM; i += 256) Wlds[i] = weight[i];
    if (tid < DIM) blds[tid] = bias[tid];
    __syncthreads();
    int lane = tid & 63;
    int wave = tid >> 6;
    int rowbase = blockIdx.x * 64 + wave * 16;
    int g = rowbase >> 10;
    const float* xg = x + ((size_t)g << 10) * DIM;
    float vmax = -INFINITY;
    for (int rr = 0; rr < 16; ++rr) {
        int row = rowbase + rr;
        const unsigned* mrow = mask + (size_t)row * MASK_WORDS;
        float acc = 0.f;
        for (int w = 0; w < MASK_WORDS; ++w) {
            unsigned bits = mrow[w];
            while (bits) {
                int b = __ffs(bits) - 1;
                bits &= bits - 1;
                acc += xg[(size_t)(w * 32 + b) * DIM + lane];
            }
        }
        float y = blds[lane];
        for (int k = 0; k < DIM; ++k) {
            float a = __shfl(acc, k, 64);
            y = fmaf(a, Wlds[k * DIM + lane], y);
        }
        vmax = fmaxf(vmax, y);
    }
    atomicMax(&pooled_u[g * DIM + lane], f2ord(vmax));
}

// ---- Tier C: fused zero-workspace fallback ----
__global__ __launch_bounds__(1024) void fused_kernel(
    const float* __restrict__ x, const int* __restrict__ ei, int E,
    const float* __restrict__ weight, const float* __restrict__ bias,
    const float* __restrict__ w1, const float* __restrict__ b1,
    const float* __restrict__ w2, const float* __restrict__ b2,
    const float* __restrict__ w3, const float* __restrict__ b3,
    float* __restrict__ out)
{
    __shared__ unsigned mask[256 * MASK_WORDS];
    __shared__ float Wlds[DIM * DIM];
    __shared__ float blds[DIM];
    __shared__ float red[16 * DIM];
    __shared__ float pool[DIM];
    __shared__ float hbuf[DIM];
    int tid = threadIdx.x;
    int g = blockIdx.x;
    int lane = tid & 63;
    int wave = tid >> 6;
    const float* xg = x + ((size_t)g << 10) * DIM;
    for (int i = tid; i < DIM * DIM; i += 1024) Wlds[i] = weight[i];
    if (tid < DIM) blds[tid] = bias[tid];
    float vmax = -INFINITY;
    for (int chunk = 0; chunk < NLOCAL / 256; ++chunk) {
        int row0 = chunk * 256;
        __syncthreads();
        for (int i = tid; i < 256 * MASK_WORDS; i += 1024) mask[i] = 0u;
        __syncthreads();
        int lo = (g << 10) + row0, hi = lo + 256;
        for (int e = tid; e < E; e += 1024) {
            int s = ei[e];
            if (s >= lo && s < hi) {
                int t = ei[E + e] & (NLOCAL - 1);
                atomicOr(&mask[(s - lo) * MASK_WORDS + (t >> 5)], 1u << (t & 31));
            }
        }
        __syncthreads();
        for (int rr = 0; rr < 256 / 16; ++rr) {
            int row = wave * (256 / 16) + rr;
            float acc = 0.f;
            for (int w = 0; w < MASK_WORDS; ++w) {
                unsigned bits = mask[row * MASK_WORDS + w];
                while (bits) {
                    int b = __ffs(bits) - 1;
                    bits &= bits - 1;
                    acc += xg[(size_t)(w * 32 + b) * DIM + lane];
                }
            }
            float y = blds[lane];
            for (int k = 0; k < DIM; ++k) {
                float a = __shfl(acc, k, 64);
                y = fmaf(a, Wlds[k * DIM + lane], y);
            }
            vmax = fmaxf(vmax, y);
        }
    }
    red[wave * DIM + lane] = vmax;
    __syncthreads();
    if (tid < DIM) {
        float m = red[tid];
        #pragma unroll
        for (int w = 1; w < 16; ++w) m = fmaxf(m, red[w * DIM + tid]);
        pool[tid] = m;
    }
    __syncthreads();
    if (tid < DIM) {
        float h = b1[tid];
        for (int k = 0; k < DIM; ++k) h = fmaf(pool[k], w1[k * DIM + tid], h);
        hbuf[tid] = tanhf(h);
    }
    __syncthreads();
    if (tid < DIM) {
        float h2 = b2[tid];
        for (int k = 0; k < DIM; ++k) h2 = fmaf(hbuf[k], w2[k * DIM + tid], h2);
        h2 = tanhf(h2);
        red[tid] = h2 * w3[tid];
    }
    __syncthreads();
    if (tid == 0) {
        float v = b3[0];
        for (int k = 0; k < DIM; ++k) v += red[k];
        out[g] = v;
    }
}

extern "C" void kernel_launch(void* const* d_in, const int* in_sizes, int n_in,
                              void* d_out, int out_size, void* d_ws, size_t ws_size,
                              hipStream_t stream)
{
    const float* x      = (const float*)d_in[0];
    const int*   ei     = (const int*)d_in[1];   // int32 (harness converts)
    const float* weight = (const float*)d_in[4];
    const float* bias   = (const float*)d_in[5];
    const float* w1     = (const float*)d_in[6];
    const float* b1     = (const float*)d_in[7];
    const float* w2     = (const float*)d_in[8];
    const float* b2     = (const float*)d_in[9];
    const float* w3     = (const float*)d_in[10];
    const float* b3     = (const float*)d_in[11];
    float* out = (float*)d_out;

    const int E = in_sizes[1] / 2;

    // Tier A layout: [pooled 16KB | done 64B | segcnt 256KB | seg 16MB | xw 16MB]
    const size_t PL_BYTES  = (size_t)NGRAPH * DIM * 4 + 64;             // +done
    const size_t SC_BYTES  = (size_t)NBIN * NBUCKET * 2;                // 256 KB
    const size_t SEG_BYTES = (size_t)NBIN * NBUCKET * SEGCAP * 4;       // 16 MB
    const size_t XW_BYTES  = (size_t)NNODES * DIM * 4;                  // 16 MB
    const size_t need_A = PL_BYTES + SC_BYTES + SEG_BYTES + XW_BYTES;
    const size_t MASKW  = (size_t)NNODES * MASK_WORDS;
    const size_t need_B = MASKW * 4 + PL_BYTES;

    if (d_ws != nullptr && ws_size >= need_A) {
        char* base = (char*)d_ws;
        unsigned*       pooled_u = (unsigned*)base;
        unsigned*       done     = (unsigned*)(base + (size_t)NGRAPH * DIM * 4);
        unsigned short* segcnt   = (unsigned short*)(base + PL_BYTES);
        unsigned*       seg      = (unsigned*)(base + PL_BYTES + SC_BYTES);
        float*          xw       = (float*)(base + PL_BYTES + SC_BYTES + SEG_BYTES);

        bin_kernel<<<NBIN, 256, 0, stream>>>(ei, E, seg, segcnt, pooled_u, done);
        xw_kernel<<<NNODES / 64, 256, 0, stream>>>(x, weight, xw);
        agg_gather_kernel<<<NBUCKET, 1024, 0, stream>>>(
            xw, bias, seg, segcnt, pooled_u, done,
            w1, b1, w2, b2, w3, b3, out);
    } else if (d_ws != nullptr && ws_size >= need_B) {
        unsigned* mask     = (unsigned*)d_ws;
        unsigned* pooled_u = mask + MASKW;
        clear_kernel<<<1024, 256, 0, stream>>>((uint4*)mask, (int)((MASKW * 4 + 16384) / 16));
        scatter_kernel<<<(E + 255) / 256, 256, 0, stream>>>(ei, mask, E);
        agg_kernel<<<NNODES / 64, 256, 0, stream>>>(x, weight, bias, mask, pooled_u);
        mlp_kernel<<<NGRAPH, DIM, 0, stream>>>(pooled_u, w1, b1, w2, b2, w3, b3, out);
    } else {
        fused_kernel<<<NGRAPH, 1024, 0, stream>>>(
            x, ei, E, weight, bias, w1, b1, w2, b2, w3, b3, out);
    }
}